// Round 3
// baseline (36.755 us; speedup 1.0000x reference)
//
#include <hip/hip_runtime.h>

#define N_NODES 207
#define N_EDGES 1722
#define N_SLOTS 288
#define L_DIM 24            // 2*12 feature channels
#define NPK 12              // packed bf16x2 words per node row (24 ch)
#define TOT_ENT (2 * N_EDGES)

typedef float f32x2 __attribute__((ext_vector_type(2)));

// CDNA packed fp32 math (gfx90a+): 2 FMAs / 2 adds per instruction.
__device__ __forceinline__ f32x2 pk_fma(f32x2 a, f32x2 b, f32x2 c) {
    f32x2 d;
    asm("v_pk_fma_f32 %0, %1, %2, %3" : "=v"(d) : "v"(a), "v"(b), "v"(c));
    return d;
}
__device__ __forceinline__ f32x2 pk_add(f32x2 a, f32x2 b) {
    f32x2 d;
    asm("v_pk_add_f32 %0, %1, %2" : "=v"(d) : "v"(a), "v"(b));
    return d;
}
// RNE pack of 2 f32 -> bf16x2 (no builtin on gfx950; see learn_hip m240)
__device__ __forceinline__ unsigned pack_bf16x2(float a, float b) {
    unsigned r;
    asm("v_cvt_pk_bf16_f32 %0, %1, %2" : "=v"(r) : "v"(a), "v"(b));
    return r;
}
// unpack bf16x2 -> f32x2: 2 VALU (shift, mask)
__device__ __forceinline__ f32x2 unpack_bf16x2(unsigned u) {
    f32x2 r;
    r.x = __uint_as_float(u << 16);
    r.y = __uint_as_float(u & 0xffff0000u);
    return r;
}

// fast tanh: 1 - 2/(e^{2x}+1); both saturation limits exact.
__device__ __forceinline__ float fast_tanhf(float x) {
    float e2 = __expf(2.0f * x);
    return 1.0f - 2.0f * __builtin_amdgcn_rcpf(e2 + 1.0f);
}

// ---------------------------------------------------------------------------
// Kernel 1: build CSR incidence (node -> (neighbor, edge_id) list), once/launch
// ---------------------------------------------------------------------------
__global__ __launch_bounds__(256) void build_csr_kernel(
    const int* __restrict__ edge_index,     // [2, N_EDGES]
    int* __restrict__ csr_off,              // [N_NODES + 1]
    unsigned int* __restrict__ entries)     // [TOT_ENT], nbr | (edge<<16)
{
    __shared__ int cnt[256];
    __shared__ int scan[256];
    __shared__ int cursor[N_NODES];
    const int tid = threadIdx.x;

    cnt[tid] = 0;
    __syncthreads();

    for (int e = tid; e < N_EDGES; e += 256) {
        int i = edge_index[e];
        int j = edge_index[N_EDGES + e];
        atomicAdd(&cnt[i], 1);
        atomicAdd(&cnt[j], 1);
    }
    __syncthreads();

    int v = (tid < N_NODES) ? cnt[tid] : 0;
    scan[tid] = v;
    __syncthreads();
    for (int s = 1; s < 256; s <<= 1) {
        int t = (tid >= s) ? scan[tid - s] : 0;
        __syncthreads();
        scan[tid] += t;
        __syncthreads();
    }
    int excl = scan[tid] - v;
    if (tid < N_NODES) { csr_off[tid] = excl; cursor[tid] = excl; }
    if (tid == 255)    { csr_off[N_NODES] = scan[255]; }
    __syncthreads();

    for (int e = tid; e < N_EDGES; e += 256) {
        int i = edge_index[e];
        int j = edge_index[N_EDGES + e];
        int pi = atomicAdd(&cursor[i], 1);
        entries[pi] = (unsigned int)j | ((unsigned int)e << 16);
        int pj = atomicAdd(&cursor[j], 1);
        entries[pj] = (unsigned int)i | ((unsigned int)e << 16);
    }
}

// ---------------------------------------------------------------------------
// Kernel 2: fused main kernel. Block = one batch element, thread w = node w.
// x staged in LDS as bf16x2 (48 B/row -> 3 ds_read_b128/entry), weights as
// interleaved (wr,wd) float2. LDS 23.7 KB -> 6 blocks/CU.
// ---------------------------------------------------------------------------
__global__ __launch_bounds__(256, 6) void rdgcn_main_kernel(
    const float* __restrict__ x_in,      // [B, 24, 207] (l-major)
    const float* __restrict__ w_react,   // [N_SLOTS, N_EDGES]
    const float* __restrict__ w_diff,    // [N_SLOTS, N_EDGES]
    const float* __restrict__ b_react,   // [N_SLOTS, N_NODES]
    const float* __restrict__ b_diff,    // [N_SLOTS, N_NODES]
    const float* __restrict__ w_self,    // [N_SLOTS, N_NODES]
    const int* __restrict__ ind,         // [B]
    const int* __restrict__ csr_off,     // [N_NODES + 1]
    const unsigned int* __restrict__ entries, // [TOT_ENT]
    float* __restrict__ out)             // [B, 207, 24]
{
    __shared__ unsigned x_sh[N_NODES * NPK];  // 9936 B, 48 B rows (16B aligned)
    __shared__ f32x2 wrd_sh[N_EDGES];         // 13776 B, (wr, wd) interleaved

    const int b   = blockIdx.x;
    const int tid = threadIdx.x;
    const int s   = ind[b];   // RESOLUTION == 1

    // Stage x: thread v gathers node row v (coalesced across lanes per l),
    // packs to bf16x2, writes 3 x b128.
    const float* xg = x_in + (size_t)b * (N_NODES * L_DIM);
    if (tid < N_NODES) {
        float row[L_DIM];
        #pragma unroll
        for (int l = 0; l < L_DIM; ++l) row[l] = xg[l * N_NODES + tid];
        unsigned pk[NPK];
        #pragma unroll
        for (int i = 0; i < NPK; ++i) pk[i] = pack_bf16x2(row[2*i], row[2*i+1]);
        uint4* dst = reinterpret_cast<uint4*>(&x_sh[tid * NPK]);
        dst[0] = make_uint4(pk[0], pk[1], pk[2],  pk[3]);
        dst[1] = make_uint4(pk[4], pk[5], pk[6],  pk[7]);
        dst[2] = make_uint4(pk[8], pk[9], pk[10], pk[11]);
    }
    {
        const float* wrg = w_react + (size_t)s * N_EDGES;
        const float* wdg = w_diff  + (size_t)s * N_EDGES;
        for (int e = tid; e < N_EDGES; e += 256) {
            f32x2 wv; wv.x = wrg[e]; wv.y = wdg[e];
            wrd_sh[e] = wv;
        }
    }
    __syncthreads();

    const int w = tid;
    if (w < N_NODES) {
        f32x2 accr[NPK], accd[NPK];
        #pragma unroll
        for (int i = 0; i < NPK; ++i) { accr[i] = (f32x2)0.f; accd[i] = (f32x2)0.f; }
        f32x2 sw2 = (f32x2)0.f;      // (d_r[w], d_d[w]) running degree sums

        const int beg = csr_off[w];
        const int end = csr_off[w + 1];
        unsigned en_cur = (beg < end) ? entries[beg] : 0u;
        for (int k = beg; k < end; ++k) {
            const unsigned en = en_cur;
            if (k + 1 < end) en_cur = entries[k + 1];
            const int nbr = (int)(en & 0xffffu);
            const int e   = (int)(en >> 16);
            const f32x2 wv = wrd_sh[e];
            sw2 = pk_add(sw2, wv);
            f32x2 wr2; wr2.x = wv.x; wr2.y = wv.x;
            f32x2 wd2; wd2.x = wv.y; wd2.y = wv.y;
            const uint4* xr = reinterpret_cast<const uint4*>(&x_sh[nbr * NPK]);
            const uint4 q0 = xr[0], q1 = xr[1], q2 = xr[2];
            #define RD_STEP(u, i) { \
                const f32x2 xv = unpack_bf16x2(u); \
                accr[i] = pk_fma(wr2, xv, accr[i]); \
                accd[i] = pk_fma(wd2, xv, accd[i]); }
            RD_STEP(q0.x, 0)  RD_STEP(q0.y, 1)  RD_STEP(q0.z, 2)  RD_STEP(q0.w, 3)
            RD_STEP(q1.x, 4)  RD_STEP(q1.y, 5)  RD_STEP(q1.z, 6)  RD_STEP(q1.w, 7)
            RD_STEP(q2.x, 8)  RD_STEP(q2.y, 9)  RD_STEP(q2.z, 10) RD_STEP(q2.w, 11)
            #undef RD_STEP
        }

        const float br  = b_react[s * N_NODES + w];
        const float bd  = b_diff [s * N_NODES + w];
        const float wsl = w_self [s * N_NODES + w];
        const float swr = sw2.x, swd = sw2.y;

        // own row (bf16-rounded) for diag + passthrough terms
        const uint4* xw = reinterpret_cast<const uint4*>(&x_sh[w * NPK]);
        const uint4 r0 = xw[0], r1 = xw[1], r2 = xw[2];
        unsigned own[NPK] = { r0.x, r0.y, r0.z, r0.w,
                              r1.x, r1.y, r1.z, r1.w,
                              r2.x, r2.y, r2.z, r2.w };
        float o[L_DIM];
        #pragma unroll
        for (int i = 0; i < NPK; ++i) {
            const f32x2 xv = unpack_bf16x2(own[i]);
            {
                float re = fmaf(swr, xv.x,  accr[i].x) + br;
                float di = fmaf(swd, xv.x, -accd[i].x) + bd;
                o[2*i]   = fast_tanhf(re) + di + fmaf(xv.x, wsl, xv.x);
            }
            {
                float re = fmaf(swr, xv.y,  accr[i].y) + br;
                float di = fmaf(swd, xv.y, -accd[i].y) + bd;
                o[2*i+1] = fast_tanhf(re) + di + fmaf(xv.y, wsl, xv.y);
            }
        }
        float4* op4 = reinterpret_cast<float4*>(out + (size_t)b * (N_NODES * L_DIM)
                                                    + (size_t)w * L_DIM);
        #pragma unroll
        for (int c = 0; c < 6; ++c)
            op4[c] = make_float4(o[4*c], o[4*c+1], o[4*c+2], o[4*c+3]);
    }
}

extern "C" void kernel_launch(void* const* d_in, const int* in_sizes, int n_in,
                              void* d_out, int out_size, void* d_ws, size_t ws_size,
                              hipStream_t stream) {
    const float* x_in     = (const float*)d_in[0];
    const float* w_react  = (const float*)d_in[1];
    const float* w_diff   = (const float*)d_in[2];
    const float* b_react  = (const float*)d_in[3];
    const float* b_diff   = (const float*)d_in[4];
    const float* w_self   = (const float*)d_in[5];
    const int*   ind      = (const int*)d_in[6];
    const int*   edge_idx = (const int*)d_in[7];
    float* out = (float*)d_out;

    int* csr_off = (int*)d_ws;
    size_t off_bytes = ((size_t)(N_NODES + 1) * sizeof(int) + 255) & ~(size_t)255;
    unsigned int* entries = (unsigned int*)((char*)d_ws + off_bytes);

    build_csr_kernel<<<1, 256, 0, stream>>>(edge_idx, csr_off, entries);

    const int B = in_sizes[6];   // 1024
    rdgcn_main_kernel<<<B, 256, 0, stream>>>(x_in, w_react, w_diff,
                                             b_react, b_diff, w_self,
                                             ind, csr_off, entries, out);
}

// Round 4
// 34.623 us; speedup vs baseline: 1.0616x; 1.0616x over previous
//
#include <hip/hip_runtime.h>

#define N_NODES 207
#define N_EDGES 1722
#define N_SLOTS 288
#define L_DIM 24            // 2*12 feature channels
#define NPK 12              // packed bf16x2 words per node row (24 ch)
#define TOT_ENT (2 * N_EDGES)

typedef float f32x2 __attribute__((ext_vector_type(2)));

// CDNA packed fp32 math (gfx90a+): 2 FMAs / adds per instruction.
__device__ __forceinline__ f32x2 pk_fma(f32x2 a, f32x2 b, f32x2 c) {
    f32x2 d;
    asm("v_pk_fma_f32 %0, %1, %2, %3" : "=v"(d) : "v"(a), "v"(b), "v"(c));
    return d;
}
__device__ __forceinline__ f32x2 pk_add(f32x2 a, f32x2 b) {
    f32x2 d;
    asm("v_pk_add_f32 %0, %1, %2" : "=v"(d) : "v"(a), "v"(b));
    return d;
}
// RNE pack of 2 f32 -> bf16x2 (no builtin on gfx950)
__device__ __forceinline__ unsigned pack_bf16x2(float a, float b) {
    unsigned r;
    asm("v_cvt_pk_bf16_f32 %0, %1, %2" : "=v"(r) : "v"(a), "v"(b));
    return r;
}
// unpack bf16x2 -> f32x2: 2 VALU
__device__ __forceinline__ f32x2 unpack_bf16x2(unsigned u) {
    f32x2 r;
    r.x = __uint_as_float(u << 16);
    r.y = __uint_as_float(u & 0xffff0000u);
    return r;
}
// fast tanh: 1 - 2/(e^{2x}+1); both saturation limits exact.
__device__ __forceinline__ float fast_tanhf(float x) {
    float e2 = __expf(2.0f * x);
    return 1.0f - 2.0f * __builtin_amdgcn_rcpf(e2 + 1.0f);
}

// ---------------------------------------------------------------------------
// Kernel 1: build CSR incidence + degree-descending node permutation.
// Single block, 256 threads, shfl-based scans (4 barriers). Runs once/launch.
// ---------------------------------------------------------------------------
__global__ __launch_bounds__(256) void build_csr_kernel(
    const int* __restrict__ edge_index,     // [2, N_EDGES]
    int* __restrict__ csr_off,              // [N_NODES + 1]
    unsigned int* __restrict__ entries,     // [TOT_ENT + 1], nbr | (edge<<16)
    int* __restrict__ perm)                 // [N_NODES] degree-desc node order
{
    __shared__ int cnt[N_NODES];
    __shared__ int cursor[N_NODES];
    __shared__ int wsum[4];
    __shared__ int dcur[64];     // degree-bucket cursors (counting sort)
    const int tid  = threadIdx.x;
    const int lane = tid & 63;
    const int wid  = tid >> 6;

    if (tid < N_NODES) cnt[tid] = 0;
    if (tid < 64) dcur[tid] = 0;
    __syncthreads();

    for (int e = tid; e < N_EDGES; e += 256) {
        int i = edge_index[e];
        int j = edge_index[N_EDGES + e];
        atomicAdd(&cnt[i], 1);
        atomicAdd(&cnt[j], 1);
    }
    __syncthreads();

    // exclusive scan of degrees over 256 slots via wave shfl-scan
    const int deg = (tid < N_NODES) ? cnt[tid] : 0;
    int x = deg;
    #pragma unroll
    for (int s = 1; s < 64; s <<= 1) {
        int t = __shfl_up(x, s, 64);
        if (lane >= s) x += t;
    }
    if (lane == 63) wsum[wid] = x;
    // degree histogram for counting sort (bucket = min(deg,63))
    int dcap = deg > 63 ? 63 : deg;
    if (tid < N_NODES) atomicAdd(&dcur[dcap], 1);
    __syncthreads();

    int base = 0;
    for (int i = 0; i < wid; ++i) base += wsum[i];
    const int excl = base + x - deg;
    if (tid < N_NODES) { csr_off[tid] = excl; cursor[tid] = excl; }
    if (tid == 255)    { csr_off[N_NODES] = base + x; entries[TOT_ENT] = 0u; }

    // descending-degree exclusive offsets: off(d) = #nodes with degree > d
    if (tid < 64) {
        int h = dcur[63 - tid];          // ascending tid = descending degree
        int xs = h;
        #pragma unroll
        for (int s = 1; s < 64; s <<= 1) {
            int t = __shfl_up(xs, s, 64);
            if (lane >= s) xs += t;
        }
        __syncthreads();                 // all reads of dcur done
        dcur[63 - tid] = xs - h;
    } else {
        __syncthreads();
    }
    __syncthreads();

    if (tid < N_NODES) {
        int p = atomicAdd(&dcur[dcap], 1);
        perm[p] = tid;
    }
    __syncthreads();

    for (int e = tid; e < N_EDGES; e += 256) {
        int i = edge_index[e];
        int j = edge_index[N_EDGES + e];
        int pi = atomicAdd(&cursor[i], 1);
        entries[pi] = (unsigned int)j | ((unsigned int)e << 16);
        int pj = atomicAdd(&cursor[j], 1);
        entries[pj] = (unsigned int)i | ((unsigned int)e << 16);
    }
}

// ---------------------------------------------------------------------------
// Kernel 2: fused main kernel. Block = batch element; thread slot tid owns
// node perm[tid] (degree-sorted so wave trip counts are balanced).
// x staged in LDS as bf16x2 (48 B/row -> 3 ds_read_b128/entry), weights as
// interleaved (wr,wd) f32x2. LDS 23.7 KB. 128-VGPR budget (4 waves/EU).
// ---------------------------------------------------------------------------
__global__ __launch_bounds__(256, 4) void rdgcn_main_kernel(
    const float* __restrict__ x_in,      // [B, 24, 207] (l-major)
    const float* __restrict__ w_react,   // [N_SLOTS, N_EDGES]
    const float* __restrict__ w_diff,    // [N_SLOTS, N_EDGES]
    const float* __restrict__ b_react,   // [N_SLOTS, N_NODES]
    const float* __restrict__ b_diff,    // [N_SLOTS, N_NODES]
    const float* __restrict__ w_self,    // [N_SLOTS, N_NODES]
    const int* __restrict__ ind,         // [B]
    const int* __restrict__ csr_off,     // [N_NODES + 1]
    const unsigned int* __restrict__ entries, // [TOT_ENT + 1] (sentinel)
    const int* __restrict__ perm,        // [N_NODES]
    float* __restrict__ out)             // [B, 207, 24]
{
    __shared__ unsigned x_sh[N_NODES * NPK];  // 9936 B, 48 B rows
    __shared__ f32x2 wrd_sh[N_EDGES];         // 13776 B

    const int b   = blockIdx.x;
    const int tid = threadIdx.x;
    const int s   = ind[b];   // RESOLUTION == 1

    // Stage x: thread v gathers node row v (coalesced across lanes per l),
    // packs to bf16x2, writes 3 x b128.
    const float* xg = x_in + (size_t)b * (N_NODES * L_DIM);
    if (tid < N_NODES) {
        float row[L_DIM];
        #pragma unroll
        for (int l = 0; l < L_DIM; ++l) row[l] = xg[l * N_NODES + tid];
        unsigned pk[NPK];
        #pragma unroll
        for (int i = 0; i < NPK; ++i) pk[i] = pack_bf16x2(row[2*i], row[2*i+1]);
        uint4* dst = reinterpret_cast<uint4*>(&x_sh[tid * NPK]);
        dst[0] = make_uint4(pk[0], pk[1], pk[2],  pk[3]);
        dst[1] = make_uint4(pk[4], pk[5], pk[6],  pk[7]);
        dst[2] = make_uint4(pk[8], pk[9], pk[10], pk[11]);
    }
    {
        const float* wrg = w_react + (size_t)s * N_EDGES;
        const float* wdg = w_diff  + (size_t)s * N_EDGES;
        for (int e = tid; e < N_EDGES; e += 256) {
            f32x2 wv; wv.x = wrg[e]; wv.y = wdg[e];
            wrd_sh[e] = wv;
        }
    }
    __syncthreads();

    if (tid >= N_NODES) return;
    const int w = perm[tid];   // degree-sorted node assignment

    f32x2 accr[NPK], accd[NPK];
    #pragma unroll
    for (int i = 0; i < NPK; ++i) { accr[i] = (f32x2)0.f; accd[i] = (f32x2)0.f; }
    f32x2 sw2 = (f32x2)0.f;      // (d_r[w], d_d[w]) running degree sums

    const int beg = csr_off[w];
    const int end = csr_off[w + 1];
    unsigned en = entries[beg];                 // safe: sentinel-padded
    for (int k = beg; k < end; ++k) {
        const unsigned en_nx = entries[k + 1];  // branchless prefetch
        const int nbr = (int)(en & 0xffffu);
        const int e   = (int)(en >> 16);
        en = en_nx;
        const f32x2 wv = wrd_sh[e];
        sw2 = pk_add(sw2, wv);
        f32x2 wr2; wr2.x = wv.x; wr2.y = wv.x;
        f32x2 wd2; wd2.x = wv.y; wd2.y = wv.y;
        const uint4* xr = reinterpret_cast<const uint4*>(&x_sh[nbr * NPK]);
        const uint4 q0 = xr[0], q1 = xr[1], q2 = xr[2];
        #define RD_STEP(u, i) { \
            const f32x2 xv = unpack_bf16x2(u); \
            accr[i] = pk_fma(wr2, xv, accr[i]); \
            accd[i] = pk_fma(wd2, xv, accd[i]); }
        RD_STEP(q0.x, 0)  RD_STEP(q0.y, 1)  RD_STEP(q0.z, 2)  RD_STEP(q0.w, 3)
        RD_STEP(q1.x, 4)  RD_STEP(q1.y, 5)  RD_STEP(q1.z, 6)  RD_STEP(q1.w, 7)
        RD_STEP(q2.x, 8)  RD_STEP(q2.y, 9)  RD_STEP(q2.z, 10) RD_STEP(q2.w, 11)
        #undef RD_STEP
    }

    const float br  = b_react[s * N_NODES + w];
    const float bd  = b_diff [s * N_NODES + w];
    const float wsl = w_self [s * N_NODES + w];
    const float swr = sw2.x, swd = sw2.y;

    // Epilogue: re-read own row quad-by-quad (keeps register count low),
    // emit 2 float4 stores per quad.
    const uint4* xw = reinterpret_cast<const uint4*>(&x_sh[w * NPK]);
    float* op = out + (size_t)b * (N_NODES * L_DIM) + (size_t)w * L_DIM;
    #pragma unroll
    for (int c = 0; c < 3; ++c) {
        const uint4 q = xw[c];
        float4 o0, o1;
        #define EP_STEP(u, j, oa, ob) { \
            const f32x2 xv = unpack_bf16x2(u); \
            float re = fmaf(swr, xv.x,  accr[j].x) + br; \
            float di = fmaf(swd, xv.x, -accd[j].x) + bd; \
            oa = fast_tanhf(re) + di + fmaf(xv.x, wsl, xv.x); \
            re = fmaf(swr, xv.y,  accr[j].y) + br; \
            di = fmaf(swd, xv.y, -accd[j].y) + bd; \
            ob = fast_tanhf(re) + di + fmaf(xv.y, wsl, xv.y); }
        EP_STEP(q.x, 4*c + 0, o0.x, o0.y)
        EP_STEP(q.y, 4*c + 1, o0.z, o0.w)
        EP_STEP(q.z, 4*c + 2, o1.x, o1.y)
        EP_STEP(q.w, 4*c + 3, o1.z, o1.w)
        #undef EP_STEP
        reinterpret_cast<float4*>(op)[2*c]     = o0;
        reinterpret_cast<float4*>(op)[2*c + 1] = o1;
    }
}

extern "C" void kernel_launch(void* const* d_in, const int* in_sizes, int n_in,
                              void* d_out, int out_size, void* d_ws, size_t ws_size,
                              hipStream_t stream) {
    const float* x_in     = (const float*)d_in[0];
    const float* w_react  = (const float*)d_in[1];
    const float* w_diff   = (const float*)d_in[2];
    const float* b_react  = (const float*)d_in[3];
    const float* b_diff   = (const float*)d_in[4];
    const float* w_self   = (const float*)d_in[5];
    const int*   ind      = (const int*)d_in[6];
    const int*   edge_idx = (const int*)d_in[7];
    float* out = (float*)d_out;

    // ws layout: csr_off [208 ints] | entries [TOT_ENT+1 u32] | perm [256 ints]
    char* wp = (char*)d_ws;
    int* csr_off = (int*)wp;
    wp += (((size_t)(N_NODES + 1) * sizeof(int)) + 255) & ~(size_t)255;
    unsigned int* entries = (unsigned int*)wp;
    wp += (((size_t)(TOT_ENT + 1) * sizeof(unsigned int)) + 255) & ~(size_t)255;
    int* perm = (int*)wp;

    build_csr_kernel<<<1, 256, 0, stream>>>(edge_idx, csr_off, entries, perm);

    const int B = in_sizes[6];   // 1024
    rdgcn_main_kernel<<<B, 256, 0, stream>>>(x_in, w_react, w_diff,
                                             b_react, b_diff, w_self,
                                             ind, csr_off, entries, perm, out);
}

// Round 5
// 32.508 us; speedup vs baseline: 1.1307x; 1.0651x over previous
//
#include <hip/hip_runtime.h>

#define N_NODES 207
#define N_EDGES 1722
#define N_SLOTS 288
#define L_DIM 24            // 2*12 feature channels
#define NPK 12              // packed bf16x2 words per node row (24 ch)
#define TOT_ENT (2 * N_EDGES)

typedef float f32x2 __attribute__((ext_vector_type(2)));

// CDNA packed fp32 math: 2 FMAs / adds per instruction (full fp32 rate path).
__device__ __forceinline__ f32x2 pk_fma(f32x2 a, f32x2 b, f32x2 c) {
    f32x2 d;
    asm("v_pk_fma_f32 %0, %1, %2, %3" : "=v"(d) : "v"(a), "v"(b), "v"(c));
    return d;
}
__device__ __forceinline__ f32x2 pk_add(f32x2 a, f32x2 b) {
    f32x2 d;
    asm("v_pk_add_f32 %0, %1, %2" : "=v"(d) : "v"(a), "v"(b));
    return d;
}
// RNE pack of 2 f32 -> bf16x2 (no builtin on gfx950)
__device__ __forceinline__ unsigned pack_bf16x2(float a, float b) {
    unsigned r;
    asm("v_cvt_pk_bf16_f32 %0, %1, %2" : "=v"(r) : "v"(a), "v"(b));
    return r;
}
// unpack bf16x2 -> f32x2: 2 VALU
__device__ __forceinline__ f32x2 unpack_bf16x2(unsigned u) {
    f32x2 r;
    r.x = __uint_as_float(u << 16);
    r.y = __uint_as_float(u & 0xffff0000u);
    return r;
}
// fast tanh: 1 - 2/(e^{2x}+1); both saturation limits exact.
__device__ __forceinline__ float fast_tanhf(float x) {
    float e2 = __expf(2.0f * x);
    return 1.0f - 2.0f * __builtin_amdgcn_rcpf(e2 + 1.0f);
}

// ---------------------------------------------------------------------------
// Kernel 1: build CSR incidence + degree-descending node permutation.
// Single block, 256 threads, shfl-based scans. Runs once per launch.
// ---------------------------------------------------------------------------
__global__ __launch_bounds__(256) void build_csr_kernel(
    const int* __restrict__ edge_index,     // [2, N_EDGES]
    int* __restrict__ csr_off,              // [N_NODES + 1]
    unsigned int* __restrict__ entries,     // [TOT_ENT + 4], nbr | (edge<<16)
    int* __restrict__ perm)                 // [N_NODES] degree-desc node order
{
    __shared__ int cnt[N_NODES];
    __shared__ int cursor[N_NODES];
    __shared__ int wsum[4];
    __shared__ int dcur[64];     // degree-bucket cursors (counting sort)
    const int tid  = threadIdx.x;
    const int lane = tid & 63;
    const int wid  = tid >> 6;

    if (tid < N_NODES) cnt[tid] = 0;
    if (tid < 64) dcur[tid] = 0;
    __syncthreads();

    for (int e = tid; e < N_EDGES; e += 256) {
        int i = edge_index[e];
        int j = edge_index[N_EDGES + e];
        atomicAdd(&cnt[i], 1);
        atomicAdd(&cnt[j], 1);
    }
    __syncthreads();

    // exclusive scan of degrees over 256 slots via wave shfl-scan
    const int deg = (tid < N_NODES) ? cnt[tid] : 0;
    int x = deg;
    #pragma unroll
    for (int s = 1; s < 64; s <<= 1) {
        int t = __shfl_up(x, s, 64);
        if (lane >= s) x += t;
    }
    if (lane == 63) wsum[wid] = x;
    // degree histogram for counting sort (bucket = min(deg,63))
    int dcap = deg > 63 ? 63 : deg;
    if (tid < N_NODES) atomicAdd(&dcur[dcap], 1);
    __syncthreads();

    int base = 0;
    for (int i = 0; i < wid; ++i) base += wsum[i];
    const int excl = base + x - deg;
    if (tid < N_NODES) { csr_off[tid] = excl; cursor[tid] = excl; }
    if (tid == 255)    { csr_off[N_NODES] = base + x; entries[TOT_ENT] = 0u; }

    // descending-degree exclusive offsets: off(d) = #nodes with degree > d
    if (tid < 64) {
        int h = dcur[63 - tid];          // ascending tid = descending degree
        int xs = h;
        #pragma unroll
        for (int s = 1; s < 64; s <<= 1) {
            int t = __shfl_up(xs, s, 64);
            if (lane >= s) xs += t;
        }
        __syncthreads();                 // all reads of dcur done
        dcur[63 - tid] = xs - h;
    } else {
        __syncthreads();
    }
    __syncthreads();

    if (tid < N_NODES) {
        int p = atomicAdd(&dcur[dcap], 1);
        perm[p] = tid;
    }
    __syncthreads();

    for (int e = tid; e < N_EDGES; e += 256) {
        int i = edge_index[e];
        int j = edge_index[N_EDGES + e];
        int pi = atomicAdd(&cursor[i], 1);
        entries[pi] = (unsigned int)j | ((unsigned int)e << 16);
        int pj = atomicAdd(&cursor[j], 1);
        entries[pj] = (unsigned int)i | ((unsigned int)e << 16);
    }
}

// ---------------------------------------------------------------------------
// Kernel 2: fused main kernel. Block = batch element; thread slot tid owns
// node perm[tid]. ALL loop-path data in LDS (entries included — the R2-R4
// versions read entries from global inside the loop with 1-deep prefetch,
// which exposed ~100cy of vmcnt stall per iteration). LDS 37.5 KB -> 4/CU.
// ---------------------------------------------------------------------------
__global__ __launch_bounds__(256, 4) void rdgcn_main_kernel(
    const float* __restrict__ x_in,      // [B, 24, 207] (l-major)
    const float* __restrict__ w_react,   // [N_SLOTS, N_EDGES]
    const float* __restrict__ w_diff,    // [N_SLOTS, N_EDGES]
    const float* __restrict__ b_react,   // [N_SLOTS, N_NODES]
    const float* __restrict__ b_diff,    // [N_SLOTS, N_NODES]
    const float* __restrict__ w_self,    // [N_SLOTS, N_NODES]
    const int* __restrict__ ind,         // [B]
    const int* __restrict__ csr_off,     // [N_NODES + 1]
    const unsigned int* __restrict__ entries, // [TOT_ENT + 4] (sentinel)
    const int* __restrict__ perm,        // [N_NODES]
    float* __restrict__ out)             // [B, 207, 24]
{
    __shared__ unsigned x_sh[N_NODES * NPK];   // 9936 B, 48 B rows
    __shared__ f32x2    wrd_sh[N_EDGES];       // 13776 B
    __shared__ unsigned ent_sh[TOT_ENT + 4];   // 13792 B  (total 37504 B)

    const int b   = blockIdx.x;
    const int tid = threadIdx.x;
    const int s   = ind[b];   // RESOLUTION == 1

    // Stage entries: uint4 coalesced (TOT_ENT = 3444 = 861*4), plus sentinel.
    {
        const uint4* eg4 = reinterpret_cast<const uint4*>(entries);
        uint4* es4 = reinterpret_cast<uint4*>(ent_sh);
        for (int k = tid; k < TOT_ENT / 4; k += 256) es4[k] = eg4[k];
        if (tid == 0) ent_sh[TOT_ENT] = 0u;
    }
    // Stage x: thread v gathers node row v (coalesced across lanes per l),
    // packs to bf16x2, writes 3 x b128.
    const float* xg = x_in + (size_t)b * (N_NODES * L_DIM);
    if (tid < N_NODES) {
        float row[L_DIM];
        #pragma unroll
        for (int l = 0; l < L_DIM; ++l) row[l] = xg[l * N_NODES + tid];
        unsigned pk[NPK];
        #pragma unroll
        for (int i = 0; i < NPK; ++i) pk[i] = pack_bf16x2(row[2*i], row[2*i+1]);
        uint4* dst = reinterpret_cast<uint4*>(&x_sh[tid * NPK]);
        dst[0] = make_uint4(pk[0], pk[1], pk[2],  pk[3]);
        dst[1] = make_uint4(pk[4], pk[5], pk[6],  pk[7]);
        dst[2] = make_uint4(pk[8], pk[9], pk[10], pk[11]);
    }
    // Stage this slot's edge weights (f32 pairs, one b64 read per entry).
    {
        const float* wrg = w_react + (size_t)s * N_EDGES;
        const float* wdg = w_diff  + (size_t)s * N_EDGES;
        for (int e = tid; e < N_EDGES; e += 256) {
            f32x2 wv; wv.x = wrg[e]; wv.y = wdg[e];
            wrd_sh[e] = wv;
        }
    }
    __syncthreads();

    if (tid >= N_NODES) return;
    const int w = perm[tid];   // degree-sorted node assignment

    // Hoist all end-of-kernel global/LDS dependencies to before the loop.
    const float br  = b_react[s * N_NODES + w];
    const float bd  = b_diff [s * N_NODES + w];
    const float wsl = w_self [s * N_NODES + w];
    const int beg = csr_off[w];
    const int end = csr_off[w + 1];
    const uint4* xw = reinterpret_cast<const uint4*>(&x_sh[w * NPK]);
    const uint4 own0 = xw[0], own1 = xw[1], own2 = xw[2];

    f32x2 accr[NPK], accd[NPK];
    #pragma unroll
    for (int i = 0; i < NPK; ++i) { accr[i] = (f32x2)0.f; accd[i] = (f32x2)0.f; }
    f32x2 sw2 = (f32x2)0.f;      // (d_r[w], d_d[w]) running degree sums

    unsigned en = ent_sh[beg];                  // sentinel-safe
    for (int k = beg; k < end; ++k) {
        const unsigned en_nx = ent_sh[k + 1];   // 1-deep LDS prefetch
        const int nbr = (int)(en & 0xffffu);
        const int e   = (int)(en >> 16);
        const f32x2 wv = wrd_sh[e];
        const uint4* xr = reinterpret_cast<const uint4*>(&x_sh[nbr * NPK]);
        const uint4 q0 = xr[0], q1 = xr[1], q2 = xr[2];
        en = en_nx;
        sw2 = pk_add(sw2, wv);
        f32x2 wr2; wr2.x = wv.x; wr2.y = wv.x;
        f32x2 wd2; wd2.x = wv.y; wd2.y = wv.y;
        #define RD_STEP(u, i) { \
            const f32x2 xv = unpack_bf16x2(u); \
            accr[i] = pk_fma(wr2, xv, accr[i]); \
            accd[i] = pk_fma(wd2, xv, accd[i]); }
        RD_STEP(q0.x, 0)  RD_STEP(q0.y, 1)  RD_STEP(q0.z, 2)  RD_STEP(q0.w, 3)
        RD_STEP(q1.x, 4)  RD_STEP(q1.y, 5)  RD_STEP(q1.z, 6)  RD_STEP(q1.w, 7)
        RD_STEP(q2.x, 8)  RD_STEP(q2.y, 9)  RD_STEP(q2.z, 10) RD_STEP(q2.w, 11)
        #undef RD_STEP
    }

    const float swr = sw2.x, swd = sw2.y;
    float* op = out + (size_t)b * (N_NODES * L_DIM) + (size_t)w * L_DIM;
    const uint4 ownq[3] = { own0, own1, own2 };
    #pragma unroll
    for (int c = 0; c < 3; ++c) {
        const uint4 q = ownq[c];
        float4 o0, o1;
        #define EP_STEP(u, j, oa, ob) { \
            const f32x2 xv = unpack_bf16x2(u); \
            float re = fmaf(swr, xv.x,  accr[j].x) + br; \
            float di = fmaf(swd, xv.x, -accd[j].x) + bd; \
            oa = fast_tanhf(re) + di + fmaf(xv.x, wsl, xv.x); \
            re = fmaf(swr, xv.y,  accr[j].y) + br; \
            di = fmaf(swd, xv.y, -accd[j].y) + bd; \
            ob = fast_tanhf(re) + di + fmaf(xv.y, wsl, xv.y); }
        EP_STEP(q.x, 4*c + 0, o0.x, o0.y)
        EP_STEP(q.y, 4*c + 1, o0.z, o0.w)
        EP_STEP(q.z, 4*c + 2, o1.x, o1.y)
        EP_STEP(q.w, 4*c + 3, o1.z, o1.w)
        #undef EP_STEP
        reinterpret_cast<float4*>(op)[2*c]     = o0;
        reinterpret_cast<float4*>(op)[2*c + 1] = o1;
    }
}

extern "C" void kernel_launch(void* const* d_in, const int* in_sizes, int n_in,
                              void* d_out, int out_size, void* d_ws, size_t ws_size,
                              hipStream_t stream) {
    const float* x_in     = (const float*)d_in[0];
    const float* w_react  = (const float*)d_in[1];
    const float* w_diff   = (const float*)d_in[2];
    const float* b_react  = (const float*)d_in[3];
    const float* b_diff   = (const float*)d_in[4];
    const float* w_self   = (const float*)d_in[5];
    const int*   ind      = (const int*)d_in[6];
    const int*   edge_idx = (const int*)d_in[7];
    float* out = (float*)d_out;

    // ws layout: csr_off [208 ints] | entries [TOT_ENT+4 u32] | perm [256 ints]
    char* wp = (char*)d_ws;
    int* csr_off = (int*)wp;
    wp += (((size_t)(N_NODES + 1) * sizeof(int)) + 255) & ~(size_t)255;
    unsigned int* entries = (unsigned int*)wp;
    wp += (((size_t)(TOT_ENT + 4) * sizeof(unsigned int)) + 255) & ~(size_t)255;
    int* perm = (int*)wp;

    build_csr_kernel<<<1, 256, 0, stream>>>(edge_idx, csr_off, entries, perm);

    const int B = in_sizes[6];   // 1024
    rdgcn_main_kernel<<<B, 256, 0, stream>>>(x_in, w_react, w_diff,
                                             b_react, b_diff, w_self,
                                             ind, csr_off, entries, perm, out);
}